// Round 10
// baseline (233.874 us; speedup 1.0000x reference)
//
#include <hip/hip_runtime.h>
#include <hip/hip_bf16.h>

// GCN layer: out = D^-1/2 (A + I) D^-1/2 (x W^T + b)
// R15: LDS-free MFMA gemm. W pre-converted ONCE to swizzled bf16 hi/lo in
//      global (folded into k_place blocks 0..63); gemm reads B-fragments
//      straight from L2 (64KB, shared by all blocks; 1KB/wave-instruction
//      coalescing), LDS 256B, 64 rows/block -> 1563 blocks, ~6 blocks/CU.
//      R14's gemm was 41.4us at 14% occupancy (64KB LDS wall + per-block
//      W re-conversion). Everything else unchanged from R14.
//   Lessons kept: no grid-sync (R11); no scattered 4B global atomics (R8);
//   private slabs (R13); spmm split in 2 for profile visibility (R14).

#define N_NODES 100000
#define N_EDGES 1600000
#define CH 128
#define NC 49            // coarse buckets of 2048 nodes
#define EPB 1024         // edges per place block
#define NBLKA 1563       // place blocks (1024 edges each)
#define CAPB 48          // slots per (bucket,block) slab: mean 20.9 + 6 sigma
#define BPU 23           // place-blocks per sortB unit
#define NCHB 68          // sortB units per coarse bucket (23*68=1564 >= 1563)
#define NFB 1563         // fine buckets of 64 nodes (1563*64 = 100032)
#define FCAP 1280        // mean 1024 + 8 sigma
#define STCAP 768        // sortB stage capacity: mean 482 + 13 sigma

using bf16x8 = __attribute__((ext_vector_type(8))) short;   // 8 bf16 in 4 VGPRs
using f32x4  = __attribute__((ext_vector_type(4))) float;   // MFMA acc

__device__ inline unsigned short f2bf(float f) {          // RNE float->bf16
    unsigned u = __float_as_uint(f);
    u += 0x7fffu + ((u >> 16) & 1u);
    return (unsigned short)(u >> 16);
}
__device__ inline float bflo(unsigned u) { return __uint_as_float(u << 16); }
__device__ inline float bfhi(unsigned u) { return __uint_as_float(u & 0xffff0000u); }

// ---------------- phase A: counting sort into private slabs (+ W conversion) -----
__global__ __launch_bounds__(256) void k_place(const int* __restrict__ src,
                                               const int* __restrict__ dst,
                                               const float* __restrict__ W,
                                               unsigned short* __restrict__ whg,
                                               unsigned short* __restrict__ wlg,
                                               int* __restrict__ cntG,
                                               unsigned* __restrict__ E1,
                                               int* __restrict__ ftail) {
    __shared__ int hist[NC];
    __shared__ int boff[NC + 1];
    __shared__ int cur[NC];
    __shared__ unsigned stage[EPB];
    const int t    = threadIdx.x;
    const int bid  = blockIdx.x;
    const int base = bid * EPB;
    const int n    = min(EPB, N_EDGES - base);    // 1024, or 512 in last block

    if (t < 2) { int i = bid * 2 + t; if (i < 1600) ftail[i] = 0; }

    // ---- W -> swizzled bf16 hi/lo in global, done once (blocks 0..63) ----
    // Same formulas as the old in-gemm cvt8 -> bit-identical hs downstream.
    if (bid < 64) {
        int idx = bid * 256 + t;                  // covers [0, 16384)
        int o = idx >> 7, kk = idx & 127;
        float v = W[idx];
        unsigned short hb = f2bf(v);
        unsigned short lb = f2bf(v - __uint_as_float((unsigned)hb << 16));
        unsigned bo = ((unsigned)((o << 8) | (kk << 1))) ^ ((unsigned)(o & 7) << 4);
        *(unsigned short*)((char*)whg + bo) = hb;
        *(unsigned short*)((char*)wlg + bo) = lb;
    }

    if (t < NC) hist[t] = 0;
    __syncthreads();

    int s[4], d[4];
    {
        int idx = 4 * t;
        if (idx < n) {                    // n in {512,1024}: int4 never straddles
            int4 sv = *(const int4*)&src[base + idx];
            int4 dv = *(const int4*)&dst[base + idx];
            s[0] = sv.x; s[1] = sv.y; s[2] = sv.z; s[3] = sv.w;
            d[0] = dv.x; d[1] = dv.y; d[2] = dv.z; d[3] = dv.w;
        } else {
            d[0] = d[1] = d[2] = d[3] = -1;
            s[0] = s[1] = s[2] = s[3] = 0;
        }
    }
#pragma unroll
    for (int j = 0; j < 4; ++j)
        if (d[j] >= 0) atomicAdd(&hist[d[j] >> 11], 1);
    __syncthreads();

    // wave-parallel inclusive scan of 49 bins (wave 0)
    if (t < 64) {
        int v = (t < NC) ? hist[t] : 0;
#pragma unroll
        for (int off = 1; off < 64; off <<= 1) {
            int u = __shfl_up(v, off, 64);
            if (t >= off) v += u;
        }
        if (t < NC) boff[t + 1] = v;
        if (t == 0) boff[0] = 0;
    }
    __syncthreads();
    if (t < NC) cur[t] = boff[t];
    __syncthreads();

#pragma unroll
    for (int j = 0; j < 4; ++j)
        if (d[j] >= 0) {
            int k = d[j] >> 11;
            int pos = atomicAdd(&cur[k], 1);
            stage[pos] = ((unsigned)s[j] << 11) | (unsigned)(d[j] & 2047);
        }
    __syncthreads();

    if (t < NC) cntG[(size_t)t * NBLKA + bid] = min(hist[t], CAPB);

    const int tot = boff[NC];
    for (int i = t; i < tot; i += 256) {
        int lo = 0, hi = NC;              // invariant: boff[lo] <= i < boff[hi]
#pragma unroll
        for (int it = 0; it < 6; ++it) {
            int mid = (lo + hi) >> 1;
            bool c = (boff[mid] <= i);
            lo = c ? mid : lo;
            hi = c ? hi : mid;
        }
        int p = i - boff[lo];
        if (p < CAPB)
            E1[((size_t)lo * NBLKA + bid) * CAPB + p] = stage[i];
    }
}

// ---------------- phase B: slabs -> 64-node fine buckets ----------------
__global__ __launch_bounds__(256) void k_sortB(const unsigned* __restrict__ E1,
                                               const int* __restrict__ cntG,
                                               int* __restrict__ ftail,
                                               unsigned* __restrict__ E2) {
    __shared__ int hist[32];
    __shared__ int boff[33];
    __shared__ int cur[32];
    __shared__ int gb[32];
    __shared__ int cnt[BPU];
    __shared__ unsigned stage[STCAP];
    const int cb  = blockIdx.x / NCHB;
    const int u   = blockIdx.x % NCHB;
    const int sb0 = u * BPU;
    const int t   = threadIdx.x;

    if (t < 32) hist[t] = 0;
    if (t < BPU) {
        int sb = sb0 + t;
        cnt[t] = (sb < NBLKA) ? cntG[(size_t)cb * NBLKA + sb] : 0;
    }
    __syncthreads();

    const unsigned* e1 = E1 + ((size_t)cb * NBLKA + sb0) * CAPB;

    for (int i = t; i < BPU * CAPB; i += 256) {
        int sb = i / CAPB, sl = i - sb * CAPB;
        if (sl < cnt[sb]) atomicAdd(&hist[(e1[i] >> 6) & 31], 1);
    }
    __syncthreads();

    if (t < 32) gb[t] = atomicAdd(&ftail[cb * 32 + t], hist[t]);
    // wave-parallel inclusive scan of 32 bins (wave 0)
    if (t < 64) {
        int v = (t < 32) ? hist[t] : 0;
#pragma unroll
        for (int off = 1; off < 32; off <<= 1) {
            int w = __shfl_up(v, off, 64);
            if (t >= off) v += w;
        }
        if (t < 32) boff[t + 1] = v;
        if (t == 0) boff[0] = 0;
    }
    __syncthreads();
    if (t < 32) cur[t] = boff[t];
    __syncthreads();

    for (int i = t; i < BPU * CAPB; i += 256) {
        int sb = i / CAPB, sl = i - sb * CAPB;
        if (sl < cnt[sb]) {
            unsigned v = e1[i];
            int k = (v >> 6) & 31;
            int pos = atomicAdd(&cur[k], 1);
            if (pos < STCAP)
                stage[pos] = ((v >> 11) << 6) | (v & 63);   // (src<<6)|(dst&63)
        }
    }
    __syncthreads();

    const int tot = min(boff[32], STCAP);
    for (int i = t; i < tot; i += 256) {
        int lo = 0, hi = 32;
#pragma unroll
        for (int it = 0; it < 5; ++it) {
            int mid = (lo + hi) >> 1;
            bool c = (boff[mid] <= i);
            lo = c ? mid : lo;
            hi = c ? hi : mid;
        }
        int p = gb[lo] + (i - boff[lo]);
        int fb = cb * 32 + lo;
        if (p < FCAP) E2[(size_t)fb * FCAP + p] = stage[i];
    }
}

// ---------------- GEMM: hs = bf16( rinv * (x W^T + b) ), LDS-free ----------------
// 64 rows/block (1 fine bucket), 4 waves x 16 rows, 8 col-frags of 16x16x32.
// Split-bf16 3-product: h ~= xh*wh + xl*wh + xh*wl (fp32-accurate).
// B-fragments read directly from L2-resident swizzled whg/wlg (64KB total).
#define MFMA(a, b, c) __builtin_amdgcn_mfma_f32_16x16x32_bf16((a), (b), (c), 0, 0, 0)

__global__ __launch_bounds__(256) void k_gemm(const float* __restrict__ x,
                                              const unsigned short* __restrict__ whg,
                                              const unsigned short* __restrict__ wlg,
                                              const float* __restrict__ b,
                                              const unsigned* __restrict__ E2,
                                              const int* __restrict__ ftail,
                                              unsigned short* __restrict__ hs) {
    __shared__ int dbin[64];
    const int t    = threadIdx.x;
    const int lane = t & 63;
    const int l15  = lane & 15;
    const int lhi  = lane >> 4;         // 0..3
    const int wid  = t >> 6;            // 0..3
    const int fb   = blockIdx.x;        // this block == fine bucket fb

    // ---- in-degree hist for this block's 64 rows ----
    if (t < 64) dbin[t] = 0;
    __syncthreads();
    {
        int n0 = ftail[fb]; if (n0 > FCAP) n0 = FCAP;
        const unsigned* e0 = E2 + (size_t)fb * FCAP;
        for (int i = t; i < n0; i += 256) atomicAdd(&dbin[e0[i] & 63], 1);
    }
    __syncthreads();
    float rreg[4];                      // rinv for this thread's 4 output rows
    {
        int lb = wid * 16 + lhi * 4;
#pragma unroll
        for (int j = 0; j < 4; ++j)
            rreg[j] = rsqrtf((float)(dbin[lb + j] + 1));
    }

    const int kc = lhi << 3;            // k-chunk base within a 32-wide k-step
    const int row_base = fb * 64 + wid * 16;
    int r0 = row_base + l15; if (r0 > N_NODES - 1) r0 = N_NODES - 1;
    const float* x0 = &x[(size_t)r0 * CH + kc];

    // issue the wave's entire x read as one burst (latency hidden once)
    float4 xa[4][2];
#pragma unroll
    for (int ks = 0; ks < 4; ++ks) {
        xa[ks][0] = *(const float4*)(x0 + ks * 32);
        xa[ks][1] = *(const float4*)(x0 + ks * 32 + 4);
    }

    f32x4 acc[8];
#pragma unroll
    for (int cf = 0; cf < 8; ++cf) acc[cf] = (f32x4){0.f, 0.f, 0.f, 0.f};

#pragma unroll
    for (int ks = 0; ks < 4; ++ks) {
        // split x into bf16 hi/lo (same math as cvt8 -> bit-identical)
        bf16x8 ah, al;
        {
            float4 a = xa[ks][0], c = xa[ks][1];
            bf16x8 H, L;
#define CV(i, f) { unsigned short hb = f2bf(f); H[i] = (short)hb;               \
                   L[i] = (short)f2bf((f) - __uint_as_float((unsigned)hb << 16)); }
            CV(0, a.x) CV(1, a.y) CV(2, a.z) CV(3, a.w)
            CV(4, c.x) CV(5, c.y) CV(6, c.z) CV(7, c.w)
#undef CV
            ah = H; al = L;
        }
        const unsigned kb = (unsigned)((ks * 32 + kc) << 1);
#pragma unroll
        for (int cf = 0; cf < 8; ++cf) {
            int o = cf * 16 + l15;
            unsigned bo = (((unsigned)(o << 8)) + kb) ^ ((unsigned)(o & 7) << 4);
            bf16x8 bh = *(const bf16x8*)((const char*)whg + bo);
            bf16x8 bl = *(const bf16x8*)((const char*)wlg + bo);
            acc[cf] = MFMA(ah, bh, acc[cf]);
            acc[cf] = MFMA(al, bh, acc[cf]);
            acc[cf] = MFMA(ah, bl, acc[cf]);
        }
    }

    // ---- epilogue: D[row=(lane>>4)*4+j][col=lane&15] per 16x16 tile ----
    float bcol[8];
#pragma unroll
    for (int cf = 0; cf < 8; ++cf) bcol[cf] = b[cf * 16 + l15];

    int rb = row_base + lhi * 4;                           // multiple of 4
    if (rb < N_NODES) {                                    // N_NODES % 4 == 0
#pragma unroll
        for (int j = 0; j < 4; ++j) {
            size_t ro = (size_t)(rb + j) * CH;
            float ri = rreg[j];
#pragma unroll
            for (int cf = 0; cf < 8; ++cf)
                hs[ro + cf * 16 + l15] = f2bf(ri * (acc[cf][j] + bcol[cf]));
        }
    }
}

// ---------------- fine-bucket SpMM: LDS sort + uint4 gather ----------------
#define ACC8(u)                                                            \
    do {                                                                   \
        acc[0] += bflo((u).x); acc[1] += bfhi((u).x);                      \
        acc[2] += bflo((u).y); acc[3] += bfhi((u).y);                      \
        acc[4] += bflo((u).z); acc[5] += bfhi((u).z);                      \
        acc[6] += bflo((u).w); acc[7] += bfhi((u).w);                      \
    } while (0)

__global__ __launch_bounds__(256) void k_spmm(const unsigned* __restrict__ E2,
                                              const int* __restrict__ ftail,
                                              const unsigned short* __restrict__ hs,
                                              float* __restrict__ out,
                                              int fb0) {
    __shared__ int bins[64];
    __shared__ int boff[65];
    __shared__ int cur[64];
    __shared__ int srt[FCAP];
    const int fb    = blockIdx.x + fb0;
    const int node0 = fb * 64;
    const int t     = threadIdx.x;
    const unsigned* e2 = E2 + (size_t)fb * FCAP;
    const uint4* hp = (const uint4*)hs;        // row s at hp[s*16 + lane]

    if (t < 64) bins[t] = 0;
    int n = ftail[fb]; if (n > FCAP) n = FCAP;
    __syncthreads();

    for (int i = t; i < n; i += 256) atomicAdd(&bins[e2[i] & 63], 1);
    __syncthreads();

    if (t == 0) {
        int run = 0;
        for (int k = 0; k < 64; ++k) { boff[k] = run; run += bins[k]; }
        boff[64] = run;
    }
    __syncthreads();
    if (t < 64) cur[t] = boff[t];
    __syncthreads();

    for (int i = t; i < n; i += 256) {
        unsigned v = e2[i];
        int pos = atomicAdd(&cur[v & 63], 1);
        srt[pos] = (int)(v >> 6);
    }
    __syncthreads();

    // gather: 16 groups x 16 lanes; group g handles nodes 4g..4g+3
    const int grp  = t >> 4;
    const int lane = t & 15;
#pragma unroll
    for (int r = 0; r < 4; ++r) {
        const int nl   = grp * 4 + r;
        const int node = node0 + nl;
        if (node >= N_NODES) continue;
        float acc[8] = {};
        {   // self term
            uint4 u = hp[(size_t)node * 16 + lane];
            ACC8(u);
        }
        int e  = boff[nl];
        int e1 = boff[nl + 1];
        for (; e + 8 <= e1; e += 8) {          // 8-deep: 128B/lane in flight
            int s0 = srt[e + 0], s1 = srt[e + 1], s2 = srt[e + 2], s3 = srt[e + 3];
            int s4 = srt[e + 4], s5 = srt[e + 5], s6 = srt[e + 6], s7 = srt[e + 7];
            uint4 u0 = hp[(size_t)s0 * 16 + lane];
            uint4 u1 = hp[(size_t)s1 * 16 + lane];
            uint4 u2 = hp[(size_t)s2 * 16 + lane];
            uint4 u3 = hp[(size_t)s3 * 16 + lane];
            uint4 u4 = hp[(size_t)s4 * 16 + lane];
            uint4 u5 = hp[(size_t)s5 * 16 + lane];
            uint4 u6 = hp[(size_t)s6 * 16 + lane];
            uint4 u7 = hp[(size_t)s7 * 16 + lane];
            ACC8(u0); ACC8(u1); ACC8(u2); ACC8(u3);
            ACC8(u4); ACC8(u5); ACC8(u6); ACC8(u7);
        }
        for (; e + 4 <= e1; e += 4) {
            int s0 = srt[e + 0];
            int s1 = srt[e + 1];
            int s2 = srt[e + 2];
            int s3 = srt[e + 3];
            uint4 u0 = hp[(size_t)s0 * 16 + lane];
            uint4 u1 = hp[(size_t)s1 * 16 + lane];
            uint4 u2 = hp[(size_t)s2 * 16 + lane];
            uint4 u3 = hp[(size_t)s3 * 16 + lane];
            ACC8(u0); ACC8(u1); ACC8(u2); ACC8(u3);
        }
        for (; e < e1; ++e) {
            uint4 u = hp[(size_t)srt[e] * 16 + lane];
            ACC8(u);
        }
        float ri = rsqrtf((float)(bins[nl] + 1));   // local rinv
        f32x4 o0, o1;
        o0[0] = ri * acc[0]; o0[1] = ri * acc[1]; o0[2] = ri * acc[2]; o0[3] = ri * acc[3];
        o1[0] = ri * acc[4]; o1[1] = ri * acc[5]; o1[2] = ri * acc[6]; o1[3] = ri * acc[7];
        *(f32x4*)&out[(size_t)node * CH + lane * 8]     = o0;
        *(f32x4*)&out[(size_t)node * CH + lane * 8 + 4] = o1;
    }
}

extern "C" void kernel_launch(void* const* d_in, const int* in_sizes, int n_in,
                              void* d_out, int out_size, void* d_ws, size_t ws_size,
                              hipStream_t stream) {
    const float* x  = (const float*)d_in[0];
    const int*   ei = (const int*)d_in[1];
    const float* W  = (const float*)d_in[2];
    const float* b  = (const float*)d_in[3];
    float* out = (float*)d_out;

    const int* src = (const int*)ei;
    const int* dst = (const int*)ei + N_EDGES;

    // workspace layout (4-byte units):
    //   ftail : 1600   (1568 used)
    //   cntG  : 49*1563 = 76587, rounded 76608
    //   whg   : 16384 bf16 = 8192 words (swizzled W hi)
    //   wlg   : 16384 bf16 = 8192 words (swizzled W lo)
    //   E2    : 1563*1280  = 2,000,640
    //   hs    : N*CH bf16  = 12,800,000 shorts (25.6 MB)
    //   E1    : ALIASES hs (49*1563*48 = 3,676,176 uints = 14.7 MB <= 25.6 MB;
    //           E1 dead after k_sortB, before k_gemm writes hs)
    int*      ftail = (int*)d_ws;
    int*      cntG  = ftail + 1600;
    unsigned short* whg = (unsigned short*)(cntG + 76608);
    unsigned short* wlg = whg + 16384;
    unsigned* E2    = (unsigned*)(wlg + 16384);
    unsigned short* hs = (unsigned short*)(E2 + (size_t)NFB * FCAP);
    unsigned* E1    = (unsigned*)hs;

    k_place<<<NBLKA, 256, 0, stream>>>(src, dst, W, whg, wlg, cntG, E1, ftail);
    k_sortB<<<NC * NCHB, 256, 0, stream>>>(E1, cntG, ftail, E2);
    k_gemm<<<NFB, 256, 0, stream>>>(x, whg, wlg, b, E2, ftail, hs);
    k_spmm<<<782, 256, 0, stream>>>(E2, ftail, hs, out, 0);
    k_spmm<<<NFB - 782, 256, 0, stream>>>(E2, ftail, hs, out, 782);
}

// Round 12
// 218.126 us; speedup vs baseline: 1.0722x; 1.0722x over previous
//
#include <hip/hip_runtime.h>
#include <hip/hip_bf16.h>

// GCN layer: out = D^-1/2 (A + I) D^-1/2 (x W^T + b)
// R16b: resubmit of R16 (infra failure, never measured). gemm = N-split LDS
//      kernel. 128 rows x 64 cols per block -> W slice is 32KB LDS (4
//      blocks/CU vs R14's 64KB/2), filled by plain uint4 copy from the
//      pre-converted swizzled whg/wlg (R15 k_place fold; no per-block
//      conversion VALU). R14 gemm: 41.4us (LDS wall, 14% occ). R15 gemm:
//      53.7us (per-MFMA L2 operand latency). This takes LDS-operand latency
//      AND high occupancy.
//   Lessons kept: no grid-sync (R11); no scattered 4B global atomics (R8);
//   private slabs (R13); spmm split in 2 for profile visibility (R14).

#define N_NODES 100000
#define N_EDGES 1600000
#define CH 128
#define NC 49            // coarse buckets of 2048 nodes
#define EPB 1024         // edges per place block
#define NBLKA 1563       // place blocks (1024 edges each)
#define CAPB 48          // slots per (bucket,block) slab: mean 20.9 + 6 sigma
#define BPU 23           // place-blocks per sortB unit
#define NCHB 68          // sortB units per coarse bucket (23*68=1564 >= 1563)
#define NFB 1563         // fine buckets of 64 nodes (1563*64 = 100032)
#define FCAP 1280        // mean 1024 + 8 sigma
#define STCAP 768        // sortB stage capacity: mean 482 + 13 sigma

using bf16x8 = __attribute__((ext_vector_type(8))) short;   // 8 bf16 in 4 VGPRs
using f32x4  = __attribute__((ext_vector_type(4))) float;   // MFMA acc

__device__ inline unsigned short f2bf(float f) {          // RNE float->bf16
    unsigned u = __float_as_uint(f);
    u += 0x7fffu + ((u >> 16) & 1u);
    return (unsigned short)(u >> 16);
}
__device__ inline float bflo(unsigned u) { return __uint_as_float(u << 16); }
__device__ inline float bfhi(unsigned u) { return __uint_as_float(u & 0xffff0000u); }

// ---------------- phase A: counting sort into private slabs (+ W conversion) -----
__global__ __launch_bounds__(256) void k_place(const int* __restrict__ src,
                                               const int* __restrict__ dst,
                                               const float* __restrict__ W,
                                               unsigned short* __restrict__ whg,
                                               unsigned short* __restrict__ wlg,
                                               int* __restrict__ cntG,
                                               unsigned* __restrict__ E1,
                                               int* __restrict__ ftail) {
    __shared__ int hist[NC];
    __shared__ int boff[NC + 1];
    __shared__ int cur[NC];
    __shared__ unsigned stage[EPB];
    const int t    = threadIdx.x;
    const int bid  = blockIdx.x;
    const int base = bid * EPB;
    const int n    = min(EPB, N_EDGES - base);    // 1024, or 512 in last block

    if (t < 2) { int i = bid * 2 + t; if (i < 1600) ftail[i] = 0; }

    // ---- W -> swizzled bf16 hi/lo in global, done once (blocks 0..63) ----
    // Same formulas as the in-gemm cvt -> bit-identical hs downstream.
    if (bid < 64) {
        int idx = bid * 256 + t;                  // covers [0, 16384)
        int o = idx >> 7, kk = idx & 127;
        float v = W[idx];
        unsigned short hb = f2bf(v);
        unsigned short lb = f2bf(v - __uint_as_float((unsigned)hb << 16));
        unsigned bo = ((unsigned)((o << 8) | (kk << 1))) ^ ((unsigned)(o & 7) << 4);
        *(unsigned short*)((char*)whg + bo) = hb;
        *(unsigned short*)((char*)wlg + bo) = lb;
    }

    if (t < NC) hist[t] = 0;
    __syncthreads();

    int s[4], d[4];
    {
        int idx = 4 * t;
        if (idx < n) {                    // n in {512,1024}: int4 never straddles
            int4 sv = *(const int4*)&src[base + idx];
            int4 dv = *(const int4*)&dst[base + idx];
            s[0] = sv.x; s[1] = sv.y; s[2] = sv.z; s[3] = sv.w;
            d[0] = dv.x; d[1] = dv.y; d[2] = dv.z; d[3] = dv.w;
        } else {
            d[0] = d[1] = d[2] = d[3] = -1;
            s[0] = s[1] = s[2] = s[3] = 0;
        }
    }
#pragma unroll
    for (int j = 0; j < 4; ++j)
        if (d[j] >= 0) atomicAdd(&hist[d[j] >> 11], 1);
    __syncthreads();

    // wave-parallel inclusive scan of 49 bins (wave 0)
    if (t < 64) {
        int v = (t < NC) ? hist[t] : 0;
#pragma unroll
        for (int off = 1; off < 64; off <<= 1) {
            int u = __shfl_up(v, off, 64);
            if (t >= off) v += u;
        }
        if (t < NC) boff[t + 1] = v;
        if (t == 0) boff[0] = 0;
    }
    __syncthreads();
    if (t < NC) cur[t] = boff[t];
    __syncthreads();

#pragma unroll
    for (int j = 0; j < 4; ++j)
        if (d[j] >= 0) {
            int k = d[j] >> 11;
            int pos = atomicAdd(&cur[k], 1);
            stage[pos] = ((unsigned)s[j] << 11) | (unsigned)(d[j] & 2047);
        }
    __syncthreads();

    if (t < NC) cntG[(size_t)t * NBLKA + bid] = min(hist[t], CAPB);

    const int tot = boff[NC];
    for (int i = t; i < tot; i += 256) {
        int lo = 0, hi = NC;              // invariant: boff[lo] <= i < boff[hi]
#pragma unroll
        for (int it = 0; it < 6; ++it) {
            int mid = (lo + hi) >> 1;
            bool c = (boff[mid] <= i);
            lo = c ? mid : lo;
            hi = c ? hi : mid;
        }
        int p = i - boff[lo];
        if (p < CAPB)
            E1[((size_t)lo * NBLKA + bid) * CAPB + p] = stage[i];
    }
}

// ---------------- phase B: slabs -> 64-node fine buckets ----------------
__global__ __launch_bounds__(256) void k_sortB(const unsigned* __restrict__ E1,
                                               const int* __restrict__ cntG,
                                               int* __restrict__ ftail,
                                               unsigned* __restrict__ E2) {
    __shared__ int hist[32];
    __shared__ int boff[33];
    __shared__ int cur[32];
    __shared__ int gb[32];
    __shared__ int cnt[BPU];
    __shared__ unsigned stage[STCAP];
    const int cb  = blockIdx.x / NCHB;
    const int u   = blockIdx.x % NCHB;
    const int sb0 = u * BPU;
    const int t   = threadIdx.x;

    if (t < 32) hist[t] = 0;
    if (t < BPU) {
        int sb = sb0 + t;
        cnt[t] = (sb < NBLKA) ? cntG[(size_t)cb * NBLKA + sb] : 0;
    }
    __syncthreads();

    const unsigned* e1 = E1 + ((size_t)cb * NBLKA + sb0) * CAPB;

    for (int i = t; i < BPU * CAPB; i += 256) {
        int sb = i / CAPB, sl = i - sb * CAPB;
        if (sl < cnt[sb]) atomicAdd(&hist[(e1[i] >> 6) & 31], 1);
    }
    __syncthreads();

    if (t < 32) gb[t] = atomicAdd(&ftail[cb * 32 + t], hist[t]);
    // wave-parallel inclusive scan of 32 bins (wave 0)
    if (t < 64) {
        int v = (t < 32) ? hist[t] : 0;
#pragma unroll
        for (int off = 1; off < 32; off <<= 1) {
            int w = __shfl_up(v, off, 64);
            if (t >= off) v += w;
        }
        if (t < 32) boff[t + 1] = v;
        if (t == 0) boff[0] = 0;
    }
    __syncthreads();
    if (t < 32) cur[t] = boff[t];
    __syncthreads();

    for (int i = t; i < BPU * CAPB; i += 256) {
        int sb = i / CAPB, sl = i - sb * CAPB;
        if (sl < cnt[sb]) {
            unsigned v = e1[i];
            int k = (v >> 6) & 31;
            int pos = atomicAdd(&cur[k], 1);
            if (pos < STCAP)
                stage[pos] = ((v >> 11) << 6) | (v & 63);   // (src<<6)|(dst&63)
        }
    }
    __syncthreads();

    const int tot = min(boff[32], STCAP);
    for (int i = t; i < tot; i += 256) {
        int lo = 0, hi = 32;
#pragma unroll
        for (int it = 0; it < 5; ++it) {
            int mid = (lo + hi) >> 1;
            bool c = (boff[mid] <= i);
            lo = c ? mid : lo;
            hi = c ? hi : mid;
        }
        int p = gb[lo] + (i - boff[lo]);
        int fb = cb * 32 + lo;
        if (p < FCAP) E2[(size_t)fb * FCAP + p] = stage[i];
    }
}

// ---------------- GEMM: hs = bf16( rinv * (x W^T + b) ), N-split LDS -------------
// 128 rows x 64 cols per block. W slice (32KB bf16 hi/lo) copied into LDS as
// plain uint4 from pre-converted whg/wlg. 4 waves x 32 rows (2 row-frags),
// 4 col-frags of 16x16x32. Split-bf16 3-product (fp32-accurate).
#define MFMA(a, b, c) __builtin_amdgcn_mfma_f32_16x16x32_bf16((a), (b), (c), 0, 0, 0)

__global__ __launch_bounds__(256) void k_gemm(const float* __restrict__ x,
                                              const unsigned short* __restrict__ whg,
                                              const unsigned short* __restrict__ wlg,
                                              const float* __restrict__ b,
                                              const unsigned* __restrict__ E2,
                                              const int* __restrict__ ftail,
                                              unsigned short* __restrict__ hs) {
    __shared__ __align__(16) unsigned short lwh[64 * CH];  // 16 KB: cols slice, hi
    __shared__ __align__(16) unsigned short lwl[64 * CH];  // 16 KB: cols slice, lo
    __shared__ int dbin[128];
    const int t    = threadIdx.x;
    const int lane = t & 63;
    const int l15  = lane & 15;
    const int lhi  = lane >> 4;         // 0..3
    const int wid  = t >> 6;            // 0..3
    const int rb_blk = blockIdx.x >> 1;
    const int c0     = (blockIdx.x & 1) << 6;   // 0 or 64

    // ---- W slice -> LDS: plain contiguous uint4 copy (swizzle preserved) ----
    {
        const uint4* wh4 = (const uint4*)whg + c0 * 16;   // c0*256B / 16
        const uint4* wl4 = (const uint4*)wlg + c0 * 16;
        uint4* lh4 = (uint4*)lwh;
        uint4* ll4 = (uint4*)lwl;
        for (int i = t; i < 1024; i += 256) {
            lh4[i] = wh4[i];
            ll4[i] = wl4[i];
        }
    }

    // ---- in-degree hist for this block's 128 rows ----
    if (t < 128) dbin[t] = 0;
    __syncthreads();
    {
        const int fb0 = rb_blk * 2;
        int n0 = ftail[fb0]; if (n0 > FCAP) n0 = FCAP;
        const unsigned* e0 = E2 + (size_t)fb0 * FCAP;
        for (int i = t; i < n0; i += 256) atomicAdd(&dbin[e0[i] & 63], 1);
        const int fb1 = fb0 + 1;
        if (fb1 < NFB) {
            int n1 = ftail[fb1]; if (n1 > FCAP) n1 = FCAP;
            const unsigned* e1p = E2 + (size_t)fb1 * FCAP;
            for (int i = t; i < n1; i += 256) atomicAdd(&dbin[64 + (e1p[i] & 63)], 1);
        }
    }
    __syncthreads();
    float rreg[2][4];                   // rinv for this thread's 8 output rows
#pragma unroll
    for (int rf = 0; rf < 2; ++rf) {
        int lb = wid * 32 + rf * 16 + lhi * 4;
#pragma unroll
        for (int j = 0; j < 4; ++j)
            rreg[rf][j] = rsqrtf((float)(dbin[lb + j] + 1));
    }

    const int kc = lhi << 3;            // k-chunk base within a 32-wide k-step
    const int row_base = rb_blk * 128 + wid * 32;
    int r0 = row_base + l15;       if (r0 > N_NODES - 1) r0 = N_NODES - 1;
    int r1 = row_base + 16 + l15;  if (r1 > N_NODES - 1) r1 = N_NODES - 1;
    const float* x0 = &x[(size_t)r0 * CH + kc];
    const float* x1 = &x[(size_t)r1 * CH + kc];

    f32x4 acc[2][4];
#pragma unroll
    for (int rf = 0; rf < 2; ++rf)
#pragma unroll
        for (int cf = 0; cf < 4; ++cf)
            acc[rf][cf] = (f32x4){0.f, 0.f, 0.f, 0.f};

    // rolling x prefetch: cur holds ks, nxt holds ks+1
    float4 ca0 = *(const float4*)(x0);
    float4 ca1 = *(const float4*)(x0 + 4);
    float4 cb0 = *(const float4*)(x1);
    float4 cb1 = *(const float4*)(x1 + 4);

#pragma unroll
    for (int ks = 0; ks < 4; ++ks) {
        float4 na0, na1, nb0, nb1;
        if (ks < 3) {
            na0 = *(const float4*)(x0 + (ks + 1) * 32);
            na1 = *(const float4*)(x0 + (ks + 1) * 32 + 4);
            nb0 = *(const float4*)(x1 + (ks + 1) * 32);
            nb1 = *(const float4*)(x1 + (ks + 1) * 32 + 4);
        }
        // split x into bf16 hi/lo (same math as before -> bit-identical)
        bf16x8 ah0, al0, ah1, al1;
        {
            bf16x8 H, L;
#define CV(i, f) { unsigned short hb = f2bf(f); H[i] = (short)hb;               \
                   L[i] = (short)f2bf((f) - __uint_as_float((unsigned)hb << 16)); }
            CV(0, ca0.x) CV(1, ca0.y) CV(2, ca0.z) CV(3, ca0.w)
            CV(4, ca1.x) CV(5, ca1.y) CV(6, ca1.z) CV(7, ca1.w)
            ah0 = H; al0 = L;
            CV(0, cb0.x) CV(1, cb0.y) CV(2, cb0.z) CV(3, cb0.w)
            CV(4, cb1.x) CV(5, cb1.y) CV(6, cb1.z) CV(7, cb1.w)
            ah1 = H; al1 = L;
#undef CV
        }
        const unsigned kb = (unsigned)((ks * 32 + kc) << 1);
#pragma unroll
        for (int cf = 0; cf < 4; ++cf) {
            int ol = cf * 16 + l15;                        // local col 0..63
            unsigned bo = (((unsigned)(ol << 8)) + kb) ^ ((unsigned)(ol & 7) << 4);
            bf16x8 bh = *(const bf16x8*)((const char*)lwh + bo);
            bf16x8 bl = *(const bf16x8*)((const char*)lwl + bo);
            acc[0][cf] = MFMA(ah0, bh, acc[0][cf]);
            acc[1][cf] = MFMA(ah1, bh, acc[1][cf]);
            acc[0][cf] = MFMA(al0, bh, acc[0][cf]);
            acc[1][cf] = MFMA(al1, bh, acc[1][cf]);
            acc[0][cf] = MFMA(ah0, bl, acc[0][cf]);
            acc[1][cf] = MFMA(ah1, bl, acc[1][cf]);
        }
        if (ks < 3) { ca0 = na0; ca1 = na1; cb0 = nb0; cb1 = nb1; }
    }

    // ---- epilogue: D[row=(lane>>4)*4+j][col=lane&15] per 16x16 tile ----
    float bcol[4];
#pragma unroll
    for (int cf = 0; cf < 4; ++cf) bcol[cf] = b[c0 + cf * 16 + l15];

#pragma unroll
    for (int rf = 0; rf < 2; ++rf) {
        int rb = row_base + rf * 16 + lhi * 4;             // multiple of 4
        if (rb >= N_NODES) continue;                       // N_NODES % 4 == 0
#pragma unroll
        for (int j = 0; j < 4; ++j) {
            size_t ro = (size_t)(rb + j) * CH + c0;
            float ri = rreg[rf][j];
#pragma unroll
            for (int cf = 0; cf < 4; ++cf)
                hs[ro + cf * 16 + l15] = f2bf(ri * (acc[rf][cf][j] + bcol[cf]));
        }
    }
}

// ---------------- fine-bucket SpMM: LDS sort + uint4 gather ----------------
#define ACC8(u)                                                            \
    do {                                                                   \
        acc[0] += bflo((u).x); acc[1] += bfhi((u).x);                      \
        acc[2] += bflo((u).y); acc[3] += bfhi((u).y);                      \
        acc[4] += bflo((u).z); acc[5] += bfhi((u).z);                      \
        acc[6] += bflo((u).w); acc[7] += bfhi((u).w);                      \
    } while (0)

__global__ __launch_bounds__(256) void k_spmm(const unsigned* __restrict__ E2,
                                              const int* __restrict__ ftail,
                                              const unsigned short* __restrict__ hs,
                                              float* __restrict__ out,
                                              int fb0) {
    __shared__ int bins[64];
    __shared__ int boff[65];
    __shared__ int cur[64];
    __shared__ int srt[FCAP];
    const int fb    = blockIdx.x + fb0;
    const int node0 = fb * 64;
    const int t     = threadIdx.x;
    const unsigned* e2 = E2 + (size_t)fb * FCAP;
    const uint4* hp = (const uint4*)hs;        // row s at hp[s*16 + lane]

    if (t < 64) bins[t] = 0;
    int n = ftail[fb]; if (n > FCAP) n = FCAP;
    __syncthreads();

    for (int i = t; i < n; i += 256) atomicAdd(&bins[e2[i] & 63], 1);
    __syncthreads();

    if (t == 0) {
        int run = 0;
        for (int k = 0; k < 64; ++k) { boff[k] = run; run += bins[k]; }
        boff[64] = run;
    }
    __syncthreads();
    if (t < 64) cur[t] = boff[t];
    __syncthreads();

    for (int i = t; i < n; i += 256) {
        unsigned v = e2[i];
        int pos = atomicAdd(&cur[v & 63], 1);
        srt[pos] = (int)(v >> 6);
    }
    __syncthreads();

    // gather: 16 groups x 16 lanes; group g handles nodes 4g..4g+3
    const int grp  = t >> 4;
    const int lane = t & 15;
#pragma unroll
    for (int r = 0; r < 4; ++r) {
        const int nl   = grp * 4 + r;
        const int node = node0 + nl;
        if (node >= N_NODES) continue;
        float acc[8] = {};
        {   // self term
            uint4 u = hp[(size_t)node * 16 + lane];
            ACC8(u);
        }
        int e  = boff[nl];
        int e1 = boff[nl + 1];
        for (; e + 8 <= e1; e += 8) {          // 8-deep: 128B/lane in flight
            int s0 = srt[e + 0], s1 = srt[e + 1], s2 = srt[e + 2], s3 = srt[e + 3];
            int s4 = srt[e + 4], s5 = srt[e + 5], s6 = srt[e + 6], s7 = srt[e + 7];
            uint4 u0 = hp[(size_t)s0 * 16 + lane];
            uint4 u1 = hp[(size_t)s1 * 16 + lane];
            uint4 u2 = hp[(size_t)s2 * 16 + lane];
            uint4 u3 = hp[(size_t)s3 * 16 + lane];
            uint4 u4 = hp[(size_t)s4 * 16 + lane];
            uint4 u5 = hp[(size_t)s5 * 16 + lane];
            uint4 u6 = hp[(size_t)s6 * 16 + lane];
            uint4 u7 = hp[(size_t)s7 * 16 + lane];
            ACC8(u0); ACC8(u1); ACC8(u2); ACC8(u3);
            ACC8(u4); ACC8(u5); ACC8(u6); ACC8(u7);
        }
        for (; e + 4 <= e1; e += 4) {
            int s0 = srt[e + 0];
            int s1 = srt[e + 1];
            int s2 = srt[e + 2];
            int s3 = srt[e + 3];
            uint4 u0 = hp[(size_t)s0 * 16 + lane];
            uint4 u1 = hp[(size_t)s1 * 16 + lane];
            uint4 u2 = hp[(size_t)s2 * 16 + lane];
            uint4 u3 = hp[(size_t)s3 * 16 + lane];
            ACC8(u0); ACC8(u1); ACC8(u2); ACC8(u3);
        }
        for (; e < e1; ++e) {
            uint4 u = hp[(size_t)srt[e] * 16 + lane];
            ACC8(u);
        }
        float ri = rsqrtf((float)(bins[nl] + 1));   // local rinv
        f32x4 o0, o1;
        o0[0] = ri * acc[0]; o0[1] = ri * acc[1]; o0[2] = ri * acc[2]; o0[3] = ri * acc[3];
        o1[0] = ri * acc[4]; o1[1] = ri * acc[5]; o1[2] = ri * acc[6]; o1[3] = ri * acc[7];
        *(f32x4*)&out[(size_t)node * CH + lane * 8]     = o0;
        *(f32x4*)&out[(size_t)node * CH + lane * 8 + 4] = o1;
    }
}

extern "C" void kernel_launch(void* const* d_in, const int* in_sizes, int n_in,
                              void* d_out, int out_size, void* d_ws, size_t ws_size,
                              hipStream_t stream) {
    const float* x  = (const float*)d_in[0];
    const int*   ei = (const int*)d_in[1];
    const float* W  = (const float*)d_in[2];
    const float* b  = (const float*)d_in[3];
    float* out = (float*)d_out;

    const int* src = (const int*)ei;
    const int* dst = (const int*)ei + N_EDGES;

    // workspace layout (4-byte units):
    //   ftail : 1600   (1568 used)
    //   cntG  : 49*1563 = 76587, rounded 76608
    //   whg   : 16384 bf16 = 8192 words (swizzled W hi)
    //   wlg   : 16384 bf16 = 8192 words (swizzled W lo)
    //   E2    : 1563*1280  = 2,000,640
    //   hs    : N*CH bf16  = 12,800,000 shorts (25.6 MB)
    //   E1    : ALIASES hs (49*1563*48 = 3,676,176 uints = 14.7 MB <= 25.6 MB;
    //           E1 dead after k_sortB, before k_gemm writes hs)
    int*      ftail = (int*)d_ws;
    int*      cntG  = ftail + 1600;
    unsigned short* whg = (unsigned short*)(cntG + 76608);
    unsigned short* wlg = whg + 16384;
    unsigned* E2    = (unsigned*)(wlg + 16384);
    unsigned short* hs = (unsigned short*)(E2 + (size_t)NFB * FCAP);
    unsigned* E1    = (unsigned*)hs;

    k_place<<<NBLKA, 256, 0, stream>>>(src, dst, W, whg, wlg, cntG, E1, ftail);
    k_sortB<<<NC * NCHB, 256, 0, stream>>>(E1, cntG, ftail, E2);
    k_gemm<<<1564, 256, 0, stream>>>(x, whg, wlg, b, E2, ftail, hs);
    k_spmm<<<782, 256, 0, stream>>>(E2, ftail, hs, out, 0);
    k_spmm<<<NFB - 782, 256, 0, stream>>>(E2, ftail, hs, out, 782);
}